// Round 6
// baseline (335.694 us; speedup 1.0000x reference)
//
#include <hip/hip_runtime.h>
#include <math.h>

// Problem constants (fixed): B=4, C=256, H=64, W=128, D=4, 81 shifts, C/R=16
// out: [B, 81, H, W] fp32 (2,654,208 elements)
// ws layout (floats): [0) pooled 82,944  [82944) At 82,944   (~663 KB)

#define HH 64
#define WW 128
#define CC 256
#define BB 4

// ---------------------------------------------------------------------------
// Kernel A: pooled[b, s, c] = sum_{h,w} f1[b,c,h,w] * f2pad[b,c,h+i,w+j]
// One 576-thread block (9 waves) per (b,c) plane. Thread = (row h = t/9,
// shift-row di = t%9) owns a full row -> w-reduction thread-private, no
// shuffles. LDS: padded f2 plane 72 x 35 float4 (40.3 KB), reused as the
// reduction buffer. Tail is now a two-stage parallel reduction using all
// 576 threads (was: 81 threads x 64-deep serial chain).
// ---------------------------------------------------------------------------
__global__ __launch_bounds__(576) void corr_pool_kernel(
    const float* __restrict__ f1, const float* __restrict__ f2,
    float* __restrict__ pooled) {
  const int t  = threadIdx.x;
  const int bc = blockIdx.x;                    // b*256 + c
  const float* f1p = f1 + (size_t)bc * (HH * WW);
  const float* f2p = f2 + (size_t)bc * (HH * WW);

  __shared__ float4 f2s4[72 * 35];              // 40,320 B; reused for reduce

  // --- stage f2 plane with zero halo (single barrier) ---
  const float4 z4 = make_float4(0.f, 0.f, 0.f, 0.f);
  for (int u = t; u < 72 * 35; u += 576) {
    const int rl = u / 35, k = u - rl * 35;     // padded row, padded chunk
    const int gr = rl - 4;                      // f2 row
    float4 v = z4;
    if ((unsigned)gr < 64u && k >= 1 && k <= 32)
      v = *(const float4*)(f2p + (gr << 7) + ((k - 1) << 2));
    f2s4[u] = v;
  }
  __syncthreads();

  // --- stage 1: thread (h, di) accumulates s9[j] over its full row ---
  const int h  = t / 9;                         // 0..63
  const int di = t - h * 9;                     // 0..8
  const float4* f2row = &f2s4[(h + di) * 35];   // padded row h+di
  const float* f1row  = f1p + (h << 7);

  float s9[9];
#pragma unroll
  for (int j = 0; j < 9; ++j) s9[j] = 0.f;

#pragma unroll 2
  for (int seg = 0; seg < 8; ++seg) {
    const int w0 = seg << 4;
    alignas(16) float f1r[16];
#pragma unroll
    for (int m = 0; m < 4; ++m)
      *(float4*)&f1r[4 * m] = *(const float4*)(f1row + w0 + (m << 2));

    alignas(16) float f2w[24];                  // padded cols w0 .. w0+23
#pragma unroll
    for (int m = 0; m < 6; ++m) *(float4*)&f2w[4 * m] = f2row[(seg << 2) + m];

#pragma unroll
    for (int k = 0; k < 16; ++k) {
      const float a = f1r[k];
#pragma unroll
      for (int j = 0; j < 9; ++j) s9[j] += a * f2w[k + j];
    }
  }

  // --- stage 2: parallel column reduction (all 576 threads) ---
  __syncthreads();                              // stage-1 LDS reads done
  float* red  = (float*)f2s4;                   // [64][81]
  float* red2 = red + 64 * 81;                  // [7][81] (23 KB total, fits)
#pragma unroll
  for (int j = 0; j < 9; ++j) red[h * 81 + di * 9 + j] = s9[j];
  __syncthreads();

  if (t < 567) {                                // 7 groups x 81 cols
    const int col = t % 81, g = t / 81;
    const int r0 = g * 9, r1 = (g == 6) ? 64 : r0 + 9;
    float acc = 0.f;
#pragma unroll 3
    for (int rr = r0; rr < r1; ++rr) acc += red[rr * 81 + col];
    red2[g * 81 + col] = acc;
  }
  __syncthreads();

  if (t < 81) {
    float acc = 0.f;
#pragma unroll
    for (int g = 0; g < 7; ++g) acc += red2[g * 81 + t];
    const int b = bc >> 8, c = bc & 255;
    pooled[(size_t)(b * 81 + t) * 256 + c] = acc;   // raw sum (/8192 in B)
  }
}

// ---------------------------------------------------------------------------
// Kernel B: At[b, c, s] = sigmoid(MLP(pooled/8192)). Transposed output for
// kernel C's wave-uniform coefficient s_loads.
// ---------------------------------------------------------------------------
__global__ __launch_bounds__(256) void mlp_kernel(
    const float* __restrict__ pooled, const float* __restrict__ w1,
    const float* __restrict__ b1, const float* __restrict__ w2,
    const float* __restrict__ b2, float* __restrict__ At) {
  const int bs = blockIdx.x;                    // b*81 + s
  const int t  = threadIdx.x;
  const int b  = bs / 81;
  const int s  = bs - b * 81;
  __shared__ float p[256];
  __shared__ float hid[16];

  p[t] = pooled[(size_t)bs * 256 + t] * (1.0f / 8192.0f);
  __syncthreads();

  const int g = t >> 4, ln = t & 15;
  float acc = 0.f;
#pragma unroll
  for (int m = 0; m < 16; ++m) {
    const int c = (m << 4) + ln;
    acc += w1[(g << 8) + c] * p[c];
  }
  acc += __shfl_xor(acc, 1);
  acc += __shfl_xor(acc, 2);
  acc += __shfl_xor(acc, 4);
  acc += __shfl_xor(acc, 8);
  if (ln == 0) hid[g] = acc + b1[g];
  __syncthreads();

  float acc2 = b2[t];
#pragma unroll
  for (int k = 0; k < 16; ++k) acc2 += w2[(t << 4) + k] * hid[k];
  const float sv = 1.0f / (1.0f + __expf(-acc2));
  At[((size_t)(b * 256 + t)) * 81 + s] = sv;    // transposed: [b][c][81]
}

// ---------------------------------------------------------------------------
// Kernel C: out[b, i*9+j, h, w] = (1/256) sum_c At[b,c,i*9+j] *
//                                  f1[c,h,w] * f2[c,h+i-4,w+j-4]
// grid = 1152 blocks (4b x 9i x 32 two-row tiles, XCD-swizzled), 256 thr =
// 4 waves = 4 channel quarters of the SAME tile -> 4x the latency-hiding
// waves/CU vs round 5, combine kernel eliminated (LDS cross-wave reduce).
// Depth-1 branchless prefetch per 64-channel stream.
// ---------------------------------------------------------------------------
__global__ __launch_bounds__(256, 5) void out_kernel(
    const float* __restrict__ f1, const float* __restrict__ f2,
    const float* __restrict__ At, float* __restrict__ out) {
  // bid = x + 8*(i + 9*tq); tile = tq*8 + x keeps i-siblings on one XCD
  const int bid  = blockIdx.x;
  const int x    = bid & 7;
  const int q    = bid >> 3;                    // 0..143
  const int i    = q % 9;
  const int tq   = q / 9;                       // 0..15
  const int tile = tq * 8 + x;                  // 0..127
  const int b    = tile >> 5;
  const int rt   = tile & 31;
  const int h0   = rt << 1;

  const int t    = threadIdx.x;
  const int wv   = t >> 6;                      // wave = channel quarter
  const int l    = t & 63;
  const int r    = l >> 5;                      // 0..1
  const int cidx = l & 31;
  const int w0   = cidx << 2;
  const int h    = h0 + r;
  const int hr   = h + i - 4;
  const bool rowok = ((unsigned)hr < 64u);

  __shared__ float redbuf[3][64][36];           // 27,648 B

  float acc[9][4];
#pragma unroll
  for (int j = 0; j < 9; ++j)
#pragma unroll
    for (int k = 0; k < 4; ++k) acc[j][k] = 0.f;

  if (rowok) {
    const int c0 = wv << 6;                     // 64-channel quarter
    const float* p1 = f1 + (size_t)b * (CC * 8192) + (size_t)c0 * 8192 +
                      (h << 7) + w0;
    const float* p2 = f2 + (size_t)b * (CC * 8192) + (size_t)c0 * 8192 +
                      (hr << 7);
    const float* Ab = At + (size_t)b * (CC * 81) + (size_t)c0 * 81 + i * 9;

    const bool vA  = (cidx > 0);
    const bool vC  = (cidx < 31);
    const int ofsA = vA ? (w0 - 4) : 0;
    const int ofsC = vC ? (w0 + 4) : 120;

    // depth-1 prefetch, branchless
    float4 nx = *(const float4*)(p1);
    float4 nA = *(const float4*)(p2 + ofsA);
    float4 nB = *(const float4*)(p2 + w0);
    float4 nC = *(const float4*)(p2 + ofsC);

    for (int c = 0; c < 64; ++c) {
      const float4 xv = nx, fA = nA, fB = nB, fC = nC;
      const int adv = (c < 63) ? 8192 : 0;      // cndmask, no branch
      p1 += adv;
      p2 += adv;
      nx = *(const float4*)(p1);
      nA = *(const float4*)(p2 + ofsA);
      nB = *(const float4*)(p2 + w0);
      nC = *(const float4*)(p2 + ofsC);

      alignas(16) float f2r[12];
      f2r[0] = vA ? fA.x : 0.f;
      f2r[1] = vA ? fA.y : 0.f;
      f2r[2] = vA ? fA.z : 0.f;
      f2r[3] = vA ? fA.w : 0.f;
      f2r[4] = fB.x; f2r[5] = fB.y; f2r[6] = fB.z; f2r[7] = fB.w;
      f2r[8]  = vC ? fC.x : 0.f;
      f2r[9]  = vC ? fC.y : 0.f;
      f2r[10] = vC ? fC.z : 0.f;
      f2r[11] = vC ? fC.w : 0.f;

      alignas(16) const float xx[4] = {xv.x, xv.y, xv.z, xv.w};

      const float* avp = Ab + (size_t)c * 81;   // wave-uniform -> s_load
#pragma unroll
      for (int j = 0; j < 9; ++j) {
        const float wj = avp[j];
#pragma unroll
        for (int k = 0; k < 4; ++k) acc[j][k] += wj * (xx[k] * f2r[k + j]);
      }
    }
  }

  // cross-wave reduction: waves 1..3 deposit, wave 0 folds and writes
  if (wv > 0) {
#pragma unroll
    for (int j = 0; j < 9; ++j)
#pragma unroll
      for (int k = 0; k < 4; ++k) redbuf[wv - 1][l][j * 4 + k] = acc[j][k];
  }
  __syncthreads();

  if (wv == 0) {
#pragma unroll
    for (int qq = 0; qq < 3; ++qq)
#pragma unroll
      for (int j = 0; j < 9; ++j)
#pragma unroll
        for (int k = 0; k < 4; ++k) acc[j][k] += redbuf[qq][l][j * 4 + k];

    const float inv = 1.0f / 256.0f;
#pragma unroll
    for (int j = 0; j < 9; ++j) {
      float4 o;
      o.x = acc[j][0] * inv;
      o.y = acc[j][1] * inv;
      o.z = acc[j][2] * inv;
      o.w = acc[j][3] * inv;
      *(float4*)(out + (((size_t)(b * 81 + i * 9 + j) * 64 + h) << 7) + w0) = o;
    }
  }
}

// ---------------------------------------------------------------------------
extern "C" void kernel_launch(void* const* d_in, const int* in_sizes, int n_in,
                              void* d_out, int out_size, void* d_ws, size_t ws_size,
                              hipStream_t stream) {
  const float* feat1 = (const float*)d_in[0];
  const float* feat2 = (const float*)d_in[1];
  const float* w1    = (const float*)d_in[2];
  const float* b1    = (const float*)d_in[3];
  const float* w2    = (const float*)d_in[4];
  const float* b2    = (const float*)d_in[5];
  float* out = (float*)d_out;

  float* pooled = (float*)d_ws;                 // 82,944 floats
  float* At     = pooled + 82944;               // 82,944 floats

  corr_pool_kernel<<<1024, 576, 0, stream>>>(feat1, feat2, pooled);
  mlp_kernel<<<4 * 81, 256, 0, stream>>>(pooled, w1, b1, w2, b2, At);
  out_kernel<<<1152, 256, 0, stream>>>(feat1, feat2, At, out);
}

// Round 7
// 200.234 us; speedup vs baseline: 1.6765x; 1.6765x over previous
//
#include <hip/hip_runtime.h>
#include <math.h>

// Problem constants (fixed): B=4, C=256, H=64, W=128, D=4, 81 shifts, C/R=16
// out: [B, 81, H, W] fp32 (2,654,208 elements)
// ws layout (floats): [0) pooled 82,944  [82944) At 82,944   (~663 KB)

#define HH 64
#define WW 128
#define CC 256
#define BB 4

// ---------------------------------------------------------------------------
// Kernel A: pooled[b, s, c] = sum_{h,w} f1[b,c,h,w] * f2pad[b,c,h+i,w+j]
// One 576-thread block (9 waves) per (b,c) plane. Thread = (row h = t/9,
// shift-row di = t%9) owns a full row -> w-reduction thread-private, no
// shuffles. LDS: padded f2 plane 72 x 35 float4 (40.3 KB), reused as the
// reduction buffer. (UNCHANGED from round 6 — isolating C's fix this round.)
// ---------------------------------------------------------------------------
__global__ __launch_bounds__(576) void corr_pool_kernel(
    const float* __restrict__ f1, const float* __restrict__ f2,
    float* __restrict__ pooled) {
  const int t  = threadIdx.x;
  const int bc = blockIdx.x;                    // b*256 + c
  const float* f1p = f1 + (size_t)bc * (HH * WW);
  const float* f2p = f2 + (size_t)bc * (HH * WW);

  __shared__ float4 f2s4[72 * 35];              // 40,320 B; reused for reduce

  // --- stage f2 plane with zero halo (single barrier) ---
  const float4 z4 = make_float4(0.f, 0.f, 0.f, 0.f);
  for (int u = t; u < 72 * 35; u += 576) {
    const int rl = u / 35, k = u - rl * 35;     // padded row, padded chunk
    const int gr = rl - 4;                      // f2 row
    float4 v = z4;
    if ((unsigned)gr < 64u && k >= 1 && k <= 32)
      v = *(const float4*)(f2p + (gr << 7) + ((k - 1) << 2));
    f2s4[u] = v;
  }
  __syncthreads();

  // --- stage 1: thread (h, di) accumulates s9[j] over its full row ---
  const int h  = t / 9;                         // 0..63
  const int di = t - h * 9;                     // 0..8
  const float4* f2row = &f2s4[(h + di) * 35];   // padded row h+di
  const float* f1row  = f1p + (h << 7);

  float s9[9];
#pragma unroll
  for (int j = 0; j < 9; ++j) s9[j] = 0.f;

#pragma unroll 2
  for (int seg = 0; seg < 8; ++seg) {
    const int w0 = seg << 4;
    alignas(16) float f1r[16];
#pragma unroll
    for (int m = 0; m < 4; ++m)
      *(float4*)&f1r[4 * m] = *(const float4*)(f1row + w0 + (m << 2));

    alignas(16) float f2w[24];                  // padded cols w0 .. w0+23
#pragma unroll
    for (int m = 0; m < 6; ++m) *(float4*)&f2w[4 * m] = f2row[(seg << 2) + m];

#pragma unroll
    for (int k = 0; k < 16; ++k) {
      const float a = f1r[k];
#pragma unroll
      for (int j = 0; j < 9; ++j) s9[j] += a * f2w[k + j];
    }
  }

  // --- stage 2: parallel column reduction (all 576 threads) ---
  __syncthreads();                              // stage-1 LDS reads done
  float* red  = (float*)f2s4;                   // [64][81]
  float* red2 = red + 64 * 81;                  // [7][81]
#pragma unroll
  for (int j = 0; j < 9; ++j) red[h * 81 + di * 9 + j] = s9[j];
  __syncthreads();

  if (t < 567) {                                // 7 groups x 81 cols
    const int col = t % 81, g = t / 81;
    const int r0 = g * 9, r1 = (g == 6) ? 64 : r0 + 9;
    float acc = 0.f;
#pragma unroll 3
    for (int rr = r0; rr < r1; ++rr) acc += red[rr * 81 + col];
    red2[g * 81 + col] = acc;
  }
  __syncthreads();

  if (t < 81) {
    float acc = 0.f;
#pragma unroll
    for (int g = 0; g < 7; ++g) acc += red2[g * 81 + t];
    const int b = bc >> 8, c = bc & 255;
    pooled[(size_t)(b * 81 + t) * 256 + c] = acc;   // raw sum (/8192 in B)
  }
}

// ---------------------------------------------------------------------------
// Kernel B: At[b, c, s] = sigmoid(MLP(pooled/8192)). Transposed output for
// kernel C's wave-uniform coefficient s_loads.
// ---------------------------------------------------------------------------
__global__ __launch_bounds__(256) void mlp_kernel(
    const float* __restrict__ pooled, const float* __restrict__ w1,
    const float* __restrict__ b1, const float* __restrict__ w2,
    const float* __restrict__ b2, float* __restrict__ At) {
  const int bs = blockIdx.x;                    // b*81 + s
  const int t  = threadIdx.x;
  const int b  = bs / 81;
  const int s  = bs - b * 81;
  __shared__ float p[256];
  __shared__ float hid[16];

  p[t] = pooled[(size_t)bs * 256 + t] * (1.0f / 8192.0f);
  __syncthreads();

  const int g = t >> 4, ln = t & 15;
  float acc = 0.f;
#pragma unroll
  for (int m = 0; m < 16; ++m) {
    const int c = (m << 4) + ln;
    acc += w1[(g << 8) + c] * p[c];
  }
  acc += __shfl_xor(acc, 1);
  acc += __shfl_xor(acc, 2);
  acc += __shfl_xor(acc, 4);
  acc += __shfl_xor(acc, 8);
  if (ln == 0) hid[g] = acc + b1[g];
  __syncthreads();

  float acc2 = b2[t];
#pragma unroll
  for (int k = 0; k < 16; ++k) acc2 += w2[(t << 4) + k] * hid[k];
  const float sv = 1.0f / (1.0f + __expf(-acc2));
  At[((size_t)(b * 256 + t)) * 81 + s] = sv;    // transposed: [b][c][81]
}

// ---------------------------------------------------------------------------
// Kernel C: out[b, i*9+j, h, w] = (1/256) sum_c At[b,c,i*9+j] *
//                                  f1[c,h,w] * f2[c,h+i-4,w+j-4]
// grid = 1152 blocks (4b x 9i x 32 two-row tiles, XCD-swizzled), 256 thr =
// 4 waves = 4 channel quarters of the SAME tile; LDS cross-wave reduce.
// __launch_bounds__(256, 4): VGPR cap 128 >> the ~52-reg live set. Round 6's
// (256,5) capped VGPRs at ~102 yet allocated 48 and spilled acc[] to scratch
// in-loop (WRITE_SIZE 365 MB, VALUBusy 13%) — do NOT tighten this bound.
// ---------------------------------------------------------------------------
__global__ __launch_bounds__(256, 4) void out_kernel(
    const float* __restrict__ f1, const float* __restrict__ f2,
    const float* __restrict__ At, float* __restrict__ out) {
  // bid = x + 8*(i + 9*tq); tile = tq*8 + x keeps i-siblings on one XCD
  const int bid  = blockIdx.x;
  const int x    = bid & 7;
  const int q    = bid >> 3;                    // 0..143
  const int i    = q % 9;
  const int tq   = q / 9;                       // 0..15
  const int tile = tq * 8 + x;                  // 0..127
  const int b    = tile >> 5;
  const int rt   = tile & 31;
  const int h0   = rt << 1;

  const int t    = threadIdx.x;
  const int wv   = t >> 6;                      // wave = channel quarter
  const int l    = t & 63;
  const int r    = l >> 5;                      // 0..1
  const int cidx = l & 31;
  const int w0   = cidx << 2;
  const int h    = h0 + r;
  const int hr   = h + i - 4;
  const bool rowok = ((unsigned)hr < 64u);

  __shared__ float redbuf[3][64][36];           // 27,648 B

  float acc[9][4];
#pragma unroll
  for (int j = 0; j < 9; ++j)
#pragma unroll
    for (int k = 0; k < 4; ++k) acc[j][k] = 0.f;

  if (rowok) {
    const int c0 = wv << 6;                     // 64-channel quarter
    const float* p1 = f1 + (size_t)b * (CC * 8192) + (size_t)c0 * 8192 +
                      (h << 7) + w0;
    const float* p2 = f2 + (size_t)b * (CC * 8192) + (size_t)c0 * 8192 +
                      (hr << 7);
    const float* Ab = At + (size_t)b * (CC * 81) + (size_t)c0 * 81 + i * 9;

    const bool vA  = (cidx > 0);
    const bool vC  = (cidx < 31);
    const int ofsA = vA ? (w0 - 4) : 0;
    const int ofsC = vC ? (w0 + 4) : 120;

    // depth-1 prefetch, branchless
    float4 nx = *(const float4*)(p1);
    float4 nA = *(const float4*)(p2 + ofsA);
    float4 nB = *(const float4*)(p2 + w0);
    float4 nC = *(const float4*)(p2 + ofsC);

    for (int c = 0; c < 64; ++c) {
      const float4 xv = nx, fA = nA, fB = nB, fC = nC;
      const int adv = (c < 63) ? 8192 : 0;      // cndmask, no branch
      p1 += adv;
      p2 += adv;
      nx = *(const float4*)(p1);
      nA = *(const float4*)(p2 + ofsA);
      nB = *(const float4*)(p2 + w0);
      nC = *(const float4*)(p2 + ofsC);

      alignas(16) float f2r[12];
      f2r[0] = vA ? fA.x : 0.f;
      f2r[1] = vA ? fA.y : 0.f;
      f2r[2] = vA ? fA.z : 0.f;
      f2r[3] = vA ? fA.w : 0.f;
      f2r[4] = fB.x; f2r[5] = fB.y; f2r[6] = fB.z; f2r[7] = fB.w;
      f2r[8]  = vC ? fC.x : 0.f;
      f2r[9]  = vC ? fC.y : 0.f;
      f2r[10] = vC ? fC.z : 0.f;
      f2r[11] = vC ? fC.w : 0.f;

      alignas(16) const float xx[4] = {xv.x, xv.y, xv.z, xv.w};

      const float* avp = Ab + (size_t)c * 81;   // wave-uniform -> s_load
#pragma unroll
      for (int j = 0; j < 9; ++j) {
        const float wj = avp[j];
#pragma unroll
        for (int k = 0; k < 4; ++k) acc[j][k] += wj * (xx[k] * f2r[k + j]);
      }
    }
  }

  // cross-wave reduction: waves 1..3 deposit, wave 0 folds and writes
  if (wv > 0) {
#pragma unroll
    for (int j = 0; j < 9; ++j)
#pragma unroll
      for (int k = 0; k < 4; ++k) redbuf[wv - 1][l][j * 4 + k] = acc[j][k];
  }
  __syncthreads();

  if (wv == 0) {
#pragma unroll
    for (int qq = 0; qq < 3; ++qq)
#pragma unroll
      for (int j = 0; j < 9; ++j)
#pragma unroll
        for (int k = 0; k < 4; ++k) acc[j][k] += redbuf[qq][l][j * 4 + k];

    const float inv = 1.0f / 256.0f;
#pragma unroll
    for (int j = 0; j < 9; ++j) {
      float4 o;
      o.x = acc[j][0] * inv;
      o.y = acc[j][1] * inv;
      o.z = acc[j][2] * inv;
      o.w = acc[j][3] * inv;
      *(float4*)(out + (((size_t)(b * 81 + i * 9 + j) * 64 + h) << 7) + w0) = o;
    }
  }
}

// ---------------------------------------------------------------------------
extern "C" void kernel_launch(void* const* d_in, const int* in_sizes, int n_in,
                              void* d_out, int out_size, void* d_ws, size_t ws_size,
                              hipStream_t stream) {
  const float* feat1 = (const float*)d_in[0];
  const float* feat2 = (const float*)d_in[1];
  const float* w1    = (const float*)d_in[2];
  const float* b1    = (const float*)d_in[3];
  const float* w2    = (const float*)d_in[4];
  const float* b2    = (const float*)d_in[5];
  float* out = (float*)d_out;

  float* pooled = (float*)d_ws;                 // 82,944 floats
  float* At     = pooled + 82944;               // 82,944 floats

  corr_pool_kernel<<<1024, 576, 0, stream>>>(feat1, feat2, pooled);
  mlp_kernel<<<4 * 81, 256, 0, stream>>>(pooled, w1, b1, w2, b2, At);
  out_kernel<<<1152, 256, 0, stream>>>(feat1, feat2, At, out);
}

// Round 8
// 197.759 us; speedup vs baseline: 1.6975x; 1.0125x over previous
//
#include <hip/hip_runtime.h>
#include <math.h>

// Problem constants (fixed): B=4, C=256, H=64, W=128, D=4, 81 shifts, C/R=16
// out: [B, 81, H, W] fp32 (2,654,208 elements)
// ws (floats): [0) pooled 82,944  [82944) At 82,944  [165888) cpart 2,654,208

#define HH 64
#define WW 128
#define CC 256
#define BB 4

// ---------------------------------------------------------------------------
// Kernel A: pooled[b, s, c] = sum_{h,w} f1[b,c,h,w] * f2pad[b,c,h+i,w+j]
// One 576-thread block (9 waves) per (b,c) plane; thread (h=t/9, di=t%9)
// owns a full row. Round-8 change: seg loop uses depth-1 prefetch of BOTH
// streams (next seg's 4 global b128 f1 + 6 LDS b128 f2 window issued before
// the current seg's 144 FMA) instead of waiting in-seg.
// ---------------------------------------------------------------------------
__global__ __launch_bounds__(576) void corr_pool_kernel(
    const float* __restrict__ f1, const float* __restrict__ f2,
    float* __restrict__ pooled) {
  const int t  = threadIdx.x;
  const int bc = blockIdx.x;                    // b*256 + c
  const float* f1p = f1 + (size_t)bc * (HH * WW);
  const float* f2p = f2 + (size_t)bc * (HH * WW);

  __shared__ float4 f2s4[72 * 35];              // 40,320 B; reused for reduce

  // --- stage f2 plane with zero halo (single barrier) ---
  const float4 z4 = make_float4(0.f, 0.f, 0.f, 0.f);
  for (int u = t; u < 72 * 35; u += 576) {
    const int rl = u / 35, k = u - rl * 35;     // padded row, padded chunk
    const int gr = rl - 4;                      // f2 row
    float4 v = z4;
    if ((unsigned)gr < 64u && k >= 1 && k <= 32)
      v = *(const float4*)(f2p + (gr << 7) + ((k - 1) << 2));
    f2s4[u] = v;
  }
  __syncthreads();

  // --- stage 1: thread (h, di) accumulates s9[j] over its full row ---
  const int h  = t / 9;                         // 0..63
  const int di = t - h * 9;                     // 0..8
  const float4* f2row = &f2s4[(h + di) * 35];   // padded row h+di
  const float* f1row  = f1p + (h << 7);

  float s9[9];
#pragma unroll
  for (int j = 0; j < 9; ++j) s9[j] = 0.f;

  alignas(16) float f1c[16], f2wc[24];
#pragma unroll
  for (int m = 0; m < 4; ++m)
    *(float4*)&f1c[4 * m] = *(const float4*)(f1row + (m << 2));
#pragma unroll
  for (int m = 0; m < 6; ++m) *(float4*)&f2wc[4 * m] = f2row[m];

  for (int seg = 0; seg < 8; ++seg) {
    const int nxt = (seg < 7) ? seg + 1 : 7;    // clamped (dup load on last)
    alignas(16) float f1n[16], f2wn[24];
#pragma unroll
    for (int m = 0; m < 4; ++m)
      *(float4*)&f1n[4 * m] =
          *(const float4*)(f1row + (nxt << 4) + (m << 2));
#pragma unroll
    for (int m = 0; m < 6; ++m) *(float4*)&f2wn[4 * m] = f2row[(nxt << 2) + m];

#pragma unroll
    for (int k = 0; k < 16; ++k) {
      const float a = f1c[k];
#pragma unroll
      for (int j = 0; j < 9; ++j) s9[j] += a * f2wc[k + j];
    }
#pragma unroll
    for (int m = 0; m < 16; ++m) f1c[m] = f1n[m];
#pragma unroll
    for (int m = 0; m < 24; ++m) f2wc[m] = f2wn[m];
  }

  // --- stage 2: parallel column reduction (all 576 threads) ---
  __syncthreads();                              // stage-1 LDS reads done
  float* red  = (float*)f2s4;                   // [64][81]
  float* red2 = red + 64 * 81;                  // [7][81]
#pragma unroll
  for (int j = 0; j < 9; ++j) red[h * 81 + di * 9 + j] = s9[j];
  __syncthreads();

  if (t < 567) {                                // 7 groups x 81 cols
    const int col = t % 81, g = t / 81;
    const int r0 = g * 9, r1 = (g == 6) ? 64 : r0 + 9;
    float acc = 0.f;
#pragma unroll 3
    for (int rr = r0; rr < r1; ++rr) acc += red[rr * 81 + col];
    red2[g * 81 + col] = acc;
  }
  __syncthreads();

  if (t < 81) {
    float acc = 0.f;
#pragma unroll
    for (int g = 0; g < 7; ++g) acc += red2[g * 81 + t];
    const int b = bc >> 8, c = bc & 255;
    pooled[(size_t)(b * 81 + t) * 256 + c] = acc;   // raw sum (/8192 in B)
  }
}

// ---------------------------------------------------------------------------
// Kernel B: At[b, c, s] = sigmoid(MLP(pooled/8192)). Transposed output for
// kernel C's wave-uniform coefficient s_loads.
// ---------------------------------------------------------------------------
__global__ __launch_bounds__(256) void mlp_kernel(
    const float* __restrict__ pooled, const float* __restrict__ w1,
    const float* __restrict__ b1, const float* __restrict__ w2,
    const float* __restrict__ b2, float* __restrict__ At) {
  const int bs = blockIdx.x;                    // b*81 + s
  const int t  = threadIdx.x;
  const int b  = bs / 81;
  const int s  = bs - b * 81;
  __shared__ float p[256];
  __shared__ float hid[16];

  p[t] = pooled[(size_t)bs * 256 + t] * (1.0f / 8192.0f);
  __syncthreads();

  const int g = t >> 4, ln = t & 15;
  float acc = 0.f;
#pragma unroll
  for (int m = 0; m < 16; ++m) {
    const int c = (m << 4) + ln;
    acc += w1[(g << 8) + c] * p[c];
  }
  acc += __shfl_xor(acc, 1);
  acc += __shfl_xor(acc, 2);
  acc += __shfl_xor(acc, 4);
  acc += __shfl_xor(acc, 8);
  if (ln == 0) hid[g] = acc + b1[g];
  __syncthreads();

  float acc2 = b2[t];
#pragma unroll
  for (int k = 0; k < 16; ++k) acc2 += w2[(t << 4) + k] * hid[k];
  const float sv = 1.0f / (1.0f + __expf(-acc2));
  At[((size_t)(b * 256 + t)) * 81 + s] = sv;    // transposed: [b][c][81]
}

// ---------------------------------------------------------------------------
// Kernel C: channel-half partial of
//   out[b, i*9+j, h, w] = (1/256) sum_c At[b,c,i*9+j]*f1[c,h,w]*f2[c,h+i-4,w+j-4]
// 2304 single-wave blocks (4b x 9i x 32 two-row tiles x 2 halves; exactly
// 9 blocks/CU, no integer tail), XCD-swizzled. DEPTH-2 vector prefetch
// (8 loads in flight; first use ~2 iterations after issue) + DEPTH-1
// coefficient prefetch (next channel's 9 floats s_loaded before this
// channel's compute). ~106 live VGPRs < the (64,4) cap of 128 — r6 lesson:
// watch WRITE_SIZE for the spill signature if this is ever tightened.
// ---------------------------------------------------------------------------
__global__ __launch_bounds__(64, 4) void out_kernel(
    const float* __restrict__ f1, const float* __restrict__ f2,
    const float* __restrict__ At, float* __restrict__ out,
    float* __restrict__ part) {
  // bid = x + 8*(i + 9*tq); tile = tq*8 + x keeps i-siblings on one XCD
  const int bid  = blockIdx.x;
  const int x    = bid & 7;
  const int q    = bid >> 3;                    // 0..287
  const int i    = q % 9;
  const int tq   = q / 9;                       // 0..31
  const int tile = tq * 8 + x;                  // 0..255
  const int half = tile & 1;
  const int rt   = (tile >> 1) & 31;
  const int b    = tile >> 6;
  const int h0   = rt << 1;

  const int t    = threadIdx.x;
  const int r    = t >> 5;                      // 0..1
  const int cidx = t & 31;
  const int w0   = cidx << 2;
  const int h    = h0 + r;
  const int hr   = h + i - 4;
  const bool rowok = ((unsigned)hr < 64u);

  float acc[9][4];
#pragma unroll
  for (int j = 0; j < 9; ++j)
#pragma unroll
    for (int k = 0; k < 4; ++k) acc[j][k] = 0.f;

  if (rowok) {
    const int c0 = half << 7;
    const float* p1 = f1 + (size_t)b * (CC * 8192) + (size_t)c0 * 8192 +
                      (h << 7) + w0;
    const float* p2 = f2 + (size_t)b * (CC * 8192) + (size_t)c0 * 8192 +
                      (hr << 7);
    const float* Ab = At + (size_t)b * (CC * 81) + (size_t)c0 * 81 + i * 9;

    const bool vA  = (cidx > 0);
    const bool vC  = (cidx < 31);
    const int ofsA = vA ? (w0 - 4) : 0;
    const int ofsC = vC ? (w0 + 4) : 120;

    // ---- pipeline init: set0 = channel 0, set1 = channel 1 ----
    float4 s0x = *(const float4*)(p1);
    float4 s0A = *(const float4*)(p2 + ofsA);
    float4 s0B = *(const float4*)(p2 + w0);
    float4 s0C = *(const float4*)(p2 + ofsC);
    p1 += 8192; p2 += 8192;
    float4 s1x = *(const float4*)(p1);
    float4 s1A = *(const float4*)(p2 + ofsA);
    float4 s1B = *(const float4*)(p2 + w0);
    float4 s1C = *(const float4*)(p2 + ofsC);

    float av[9];
#pragma unroll
    for (int j = 0; j < 9; ++j) av[j] = Ab[j];  // coeffs for c=0
    const float* qa = Ab + 81;                  // points at c=1

    for (int c = 0; c < 128; ++c) {
      // issue vector loads for channel min(c+2,127)
      const int adv = (c < 126) ? 8192 : 0;
      p1 += adv; p2 += adv;
      const float4 nx = *(const float4*)(p1);
      const float4 nA = *(const float4*)(p2 + ofsA);
      const float4 nB = *(const float4*)(p2 + w0);
      const float4 nC = *(const float4*)(p2 + ofsC);

      // issue coefficient loads for channel min(c+1,127)
      float avn[9];
#pragma unroll
      for (int j = 0; j < 9; ++j) avn[j] = qa[j];  // wave-uniform -> s_load

      // compute channel c from set0 + av
      alignas(16) float f2r[12];
      f2r[0] = vA ? s0A.x : 0.f;
      f2r[1] = vA ? s0A.y : 0.f;
      f2r[2] = vA ? s0A.z : 0.f;
      f2r[3] = vA ? s0A.w : 0.f;
      f2r[4] = s0B.x; f2r[5] = s0B.y; f2r[6] = s0B.z; f2r[7] = s0B.w;
      f2r[8]  = vC ? s0C.x : 0.f;
      f2r[9]  = vC ? s0C.y : 0.f;
      f2r[10] = vC ? s0C.z : 0.f;
      f2r[11] = vC ? s0C.w : 0.f;

      alignas(16) const float xx[4] = {s0x.x, s0x.y, s0x.z, s0x.w};

#pragma unroll
      for (int j = 0; j < 9; ++j) {
        const float wj = av[j];
#pragma unroll
        for (int k = 0; k < 4; ++k) acc[j][k] += wj * (xx[k] * f2r[k + j]);
      }

      // rotate pipeline
      s0x = s1x; s0A = s1A; s0B = s1B; s0C = s1C;
      s1x = nx;  s1A = nA;  s1B = nB;  s1C = nC;
#pragma unroll
      for (int j = 0; j < 9; ++j) av[j] = avn[j];
      qa += (c < 126) ? 81 : 0;
    }
  }

  float* dst = half ? part : out;
  const float inv = 1.0f / 256.0f;
#pragma unroll
  for (int j = 0; j < 9; ++j) {
    float4 o;
    o.x = acc[j][0] * inv;
    o.y = acc[j][1] * inv;
    o.z = acc[j][2] * inv;
    o.w = acc[j][3] * inv;
    *(float4*)(dst + (((size_t)(b * 81 + i * 9 + j) * 64 + h) << 7) + w0) = o;
  }
}

// ---------------------------------------------------------------------------
// Combine: out += channel-half-1 partial. 663,552 float4s, grid 2592 x 256.
// ---------------------------------------------------------------------------
__global__ __launch_bounds__(256) void combine_kernel(
    float* __restrict__ out, const float* __restrict__ part) {
  const size_t idx = (size_t)blockIdx.x * 256 + threadIdx.x;  // float4 index
  float4* o4       = (float4*)out;
  const float4* p4 = (const float4*)part;
  const float4 a = o4[idx], p = p4[idx];
  float4 rv;
  rv.x = a.x + p.x; rv.y = a.y + p.y; rv.z = a.z + p.z; rv.w = a.w + p.w;
  o4[idx] = rv;
}

// ---------------------------------------------------------------------------
extern "C" void kernel_launch(void* const* d_in, const int* in_sizes, int n_in,
                              void* d_out, int out_size, void* d_ws, size_t ws_size,
                              hipStream_t stream) {
  const float* feat1 = (const float*)d_in[0];
  const float* feat2 = (const float*)d_in[1];
  const float* w1    = (const float*)d_in[2];
  const float* b1    = (const float*)d_in[3];
  const float* w2    = (const float*)d_in[4];
  const float* b2    = (const float*)d_in[5];
  float* out = (float*)d_out;

  float* pooled = (float*)d_ws;                 // 82,944 floats
  float* At     = pooled + 82944;               // 82,944 floats
  float* cpart  = At + 82944;                   // 2,654,208 floats

  corr_pool_kernel<<<1024, 576, 0, stream>>>(feat1, feat2, pooled);
  mlp_kernel<<<4 * 81, 256, 0, stream>>>(pooled, w1, b1, w2, b2, At);
  out_kernel<<<2304, 64, 0, stream>>>(feat1, feat2, At, out, cpart);
  combine_kernel<<<2592, 256, 0, stream>>>(out, cpart);
}

// Round 9
// 190.673 us; speedup vs baseline: 1.7606x; 1.0372x over previous
//
#include <hip/hip_runtime.h>
#include <math.h>

// Problem constants (fixed): B=4, C=256, H=64, W=128, D=4, 81 shifts, C/R=16
// out: [B, 81, H, W] fp32 (2,654,208 elements)
// ws (floats): [0) pooled 82,944  [82944) At 82,944  [165888) cpart 2,654,208

#define HH 64
#define WW 128
#define CC 256
#define BB 4

// ---------------------------------------------------------------------------
// Kernel A: pooled[b, s, c] = sum_{h,w} f1[b,c,h,w] * f2pad[b,c,h+i,w+j]
// One 576-thread block (9 waves) per (b,c) plane; thread (h=t/9, di=t%9)
// owns a full row. UNCHANGED from round 8 (isolating C's change; C should
// now be fast enough that A finally appears in the top-5 counters).
// ---------------------------------------------------------------------------
__global__ __launch_bounds__(576) void corr_pool_kernel(
    const float* __restrict__ f1, const float* __restrict__ f2,
    float* __restrict__ pooled) {
  const int t  = threadIdx.x;
  const int bc = blockIdx.x;                    // b*256 + c
  const float* f1p = f1 + (size_t)bc * (HH * WW);
  const float* f2p = f2 + (size_t)bc * (HH * WW);

  __shared__ float4 f2s4[72 * 35];              // 40,320 B; reused for reduce

  // --- stage f2 plane with zero halo (single barrier) ---
  const float4 z4 = make_float4(0.f, 0.f, 0.f, 0.f);
  for (int u = t; u < 72 * 35; u += 576) {
    const int rl = u / 35, k = u - rl * 35;     // padded row, padded chunk
    const int gr = rl - 4;                      // f2 row
    float4 v = z4;
    if ((unsigned)gr < 64u && k >= 1 && k <= 32)
      v = *(const float4*)(f2p + (gr << 7) + ((k - 1) << 2));
    f2s4[u] = v;
  }
  __syncthreads();

  // --- stage 1: thread (h, di) accumulates s9[j] over its full row ---
  const int h  = t / 9;                         // 0..63
  const int di = t - h * 9;                     // 0..8
  const float4* f2row = &f2s4[(h + di) * 35];   // padded row h+di
  const float* f1row  = f1p + (h << 7);

  float s9[9];
#pragma unroll
  for (int j = 0; j < 9; ++j) s9[j] = 0.f;

  alignas(16) float f1c[16], f2wc[24];
#pragma unroll
  for (int m = 0; m < 4; ++m)
    *(float4*)&f1c[4 * m] = *(const float4*)(f1row + (m << 2));
#pragma unroll
  for (int m = 0; m < 6; ++m) *(float4*)&f2wc[4 * m] = f2row[m];

  for (int seg = 0; seg < 8; ++seg) {
    const int nxt = (seg < 7) ? seg + 1 : 7;    // clamped (dup load on last)
    alignas(16) float f1n[16], f2wn[24];
#pragma unroll
    for (int m = 0; m < 4; ++m)
      *(float4*)&f1n[4 * m] =
          *(const float4*)(f1row + (nxt << 4) + (m << 2));
#pragma unroll
    for (int m = 0; m < 6; ++m) *(float4*)&f2wn[4 * m] = f2row[(nxt << 2) + m];

#pragma unroll
    for (int k = 0; k < 16; ++k) {
      const float a = f1c[k];
#pragma unroll
      for (int j = 0; j < 9; ++j) s9[j] += a * f2wc[k + j];
    }
#pragma unroll
    for (int m = 0; m < 16; ++m) f1c[m] = f1n[m];
#pragma unroll
    for (int m = 0; m < 24; ++m) f2wc[m] = f2wn[m];
  }

  // --- stage 2: parallel column reduction (all 576 threads) ---
  __syncthreads();                              // stage-1 LDS reads done
  float* red  = (float*)f2s4;                   // [64][81]
  float* red2 = red + 64 * 81;                  // [7][81]
#pragma unroll
  for (int j = 0; j < 9; ++j) red[h * 81 + di * 9 + j] = s9[j];
  __syncthreads();

  if (t < 567) {                                // 7 groups x 81 cols
    const int col = t % 81, g = t / 81;
    const int r0 = g * 9, r1 = (g == 6) ? 64 : r0 + 9;
    float acc = 0.f;
#pragma unroll 3
    for (int rr = r0; rr < r1; ++rr) acc += red[rr * 81 + col];
    red2[g * 81 + col] = acc;
  }
  __syncthreads();

  if (t < 81) {
    float acc = 0.f;
#pragma unroll
    for (int g = 0; g < 7; ++g) acc += red2[g * 81 + t];
    const int b = bc >> 8, c = bc & 255;
    pooled[(size_t)(b * 81 + t) * 256 + c] = acc;   // raw sum (/8192 in B)
  }
}

// ---------------------------------------------------------------------------
// Kernel B: At[b, c, s] = sigmoid(MLP(pooled/8192)). Transposed output for
// kernel C's wave-uniform coefficient s_loads.
// ---------------------------------------------------------------------------
__global__ __launch_bounds__(256) void mlp_kernel(
    const float* __restrict__ pooled, const float* __restrict__ w1,
    const float* __restrict__ b1, const float* __restrict__ w2,
    const float* __restrict__ b2, float* __restrict__ At) {
  const int bs = blockIdx.x;                    // b*81 + s
  const int t  = threadIdx.x;
  const int b  = bs / 81;
  const int s  = bs - b * 81;
  __shared__ float p[256];
  __shared__ float hid[16];

  p[t] = pooled[(size_t)bs * 256 + t] * (1.0f / 8192.0f);
  __syncthreads();

  const int g = t >> 4, ln = t & 15;
  float acc = 0.f;
#pragma unroll
  for (int m = 0; m < 16; ++m) {
    const int c = (m << 4) + ln;
    acc += w1[(g << 8) + c] * p[c];
  }
  acc += __shfl_xor(acc, 1);
  acc += __shfl_xor(acc, 2);
  acc += __shfl_xor(acc, 4);
  acc += __shfl_xor(acc, 8);
  if (ln == 0) hid[g] = acc + b1[g];
  __syncthreads();

  float acc2 = b2[t];
#pragma unroll
  for (int k = 0; k < 16; ++k) acc2 += w2[(t << 4) + k] * hid[k];
  const float sv = 1.0f / (1.0f + __expf(-acc2));
  At[((size_t)(b * 256 + t)) * 81 + s] = sv;    // transposed: [b][c][81]
}

// ---------------------------------------------------------------------------
// Kernel C: channel-half partial of
//   out[b, i*9+j, h, w] = (1/256) sum_c At[b,c,i*9+j]*f1[c,h,w]*f2[c,h+i-4,w+j-4]
// 2304 single-wave blocks (4b x 9i x 32 two-row tiles x 2 halves), XCD-
// swizzled. Round-9: CHANNEL PAIRING — each iteration processes channels
// c and c+64 (8 float4 loads batched up front, 2x compute per latency
// window). The compiler cannot re-serialize this the way it deleted the
// r8 rotation pipeline (VGPR_Count 40): both channels' loads must complete
// before this iteration's FMAs, so they issue as one batch. 64 iters.
// Watch: WRITE_SIZE >> 21 MB here means the pair spilled (r6 signature).
// ---------------------------------------------------------------------------
__global__ __launch_bounds__(64, 4) void out_kernel(
    const float* __restrict__ f1, const float* __restrict__ f2,
    const float* __restrict__ At, float* __restrict__ out,
    float* __restrict__ part) {
  // bid = x + 8*(i + 9*tq); tile = tq*8 + x keeps i-siblings on one XCD
  const int bid  = blockIdx.x;
  const int x    = bid & 7;
  const int q    = bid >> 3;                    // 0..287
  const int i    = q % 9;
  const int tq   = q / 9;                       // 0..31
  const int tile = tq * 8 + x;                  // 0..255
  const int half = tile & 1;
  const int rt   = (tile >> 1) & 31;
  const int b    = tile >> 6;
  const int h0   = rt << 1;

  const int t    = threadIdx.x;
  const int r    = t >> 5;                      // 0..1
  const int cidx = t & 31;
  const int w0   = cidx << 2;
  const int h    = h0 + r;
  const int hr   = h + i - 4;
  const bool rowok = ((unsigned)hr < 64u);

  float acc[9][4];
#pragma unroll
  for (int j = 0; j < 9; ++j)
#pragma unroll
    for (int k = 0; k < 4; ++k) acc[j][k] = 0.f;

  if (rowok) {
    const int c0 = half << 7;                   // 128-channel half base
    const float* pa1 = f1 + (size_t)b * (CC * 8192) + (size_t)c0 * 8192 +
                       (h << 7) + w0;
    const float* pa2 = f2 + (size_t)b * (CC * 8192) + (size_t)c0 * 8192 +
                       (hr << 7);
    const float* pb1 = pa1 + (size_t)64 * 8192; // paired channel c+64
    const float* pb2 = pa2 + (size_t)64 * 8192;
    const float* Aa  = At + (size_t)b * (CC * 81) + (size_t)c0 * 81 + i * 9;

    const bool vA  = (cidx > 0);
    const bool vC  = (cidx < 31);
    const int ofsA = vA ? (w0 - 4) : 0;
    const int ofsC = vC ? (w0 + 4) : 120;

    for (int c = 0; c < 64; ++c) {
      // --- batch all 8 vector loads (two channels) ---
      const float4 xa = *(const float4*)(pa1);
      const float4 aA = *(const float4*)(pa2 + ofsA);
      const float4 aB = *(const float4*)(pa2 + w0);
      const float4 aC = *(const float4*)(pa2 + ofsC);
      const float4 xb = *(const float4*)(pb1);
      const float4 bA = *(const float4*)(pb2 + ofsA);
      const float4 bB = *(const float4*)(pb2 + w0);
      const float4 bC = *(const float4*)(pb2 + ofsC);

      const float* ca = Aa + (size_t)c * 81;    // wave-uniform -> s_load
      const float* cb = ca + (size_t)64 * 81;

      const int adv = (c < 63) ? 8192 : 0;      // cndmask, no branch
      pa1 += adv; pa2 += adv; pb1 += adv; pb2 += adv;

      // --- channel a ---
      alignas(16) float f2ra[12];
      f2ra[0] = vA ? aA.x : 0.f;
      f2ra[1] = vA ? aA.y : 0.f;
      f2ra[2] = vA ? aA.z : 0.f;
      f2ra[3] = vA ? aA.w : 0.f;
      f2ra[4] = aB.x; f2ra[5] = aB.y; f2ra[6] = aB.z; f2ra[7] = aB.w;
      f2ra[8]  = vC ? aC.x : 0.f;
      f2ra[9]  = vC ? aC.y : 0.f;
      f2ra[10] = vC ? aC.z : 0.f;
      f2ra[11] = vC ? aC.w : 0.f;
      alignas(16) const float xxa[4] = {xa.x, xa.y, xa.z, xa.w};

#pragma unroll
      for (int j = 0; j < 9; ++j) {
        const float wj = ca[j];
#pragma unroll
        for (int k = 0; k < 4; ++k) acc[j][k] += wj * (xxa[k] * f2ra[k + j]);
      }

      // --- channel b (c+64) ---
      alignas(16) float f2rb[12];
      f2rb[0] = vA ? bA.x : 0.f;
      f2rb[1] = vA ? bA.y : 0.f;
      f2rb[2] = vA ? bA.z : 0.f;
      f2rb[3] = vA ? bA.w : 0.f;
      f2rb[4] = bB.x; f2rb[5] = bB.y; f2rb[6] = bB.z; f2rb[7] = bB.w;
      f2rb[8]  = vC ? bC.x : 0.f;
      f2rb[9]  = vC ? bC.y : 0.f;
      f2rb[10] = vC ? bC.z : 0.f;
      f2rb[11] = vC ? bC.w : 0.f;
      alignas(16) const float xxb[4] = {xb.x, xb.y, xb.z, xb.w};

#pragma unroll
      for (int j = 0; j < 9; ++j) {
        const float wj = cb[j];
#pragma unroll
        for (int k = 0; k < 4; ++k) acc[j][k] += wj * (xxb[k] * f2rb[k + j]);
      }
    }
  }

  float* dst = half ? part : out;
  const float inv = 1.0f / 256.0f;
#pragma unroll
  for (int j = 0; j < 9; ++j) {
    float4 o;
    o.x = acc[j][0] * inv;
    o.y = acc[j][1] * inv;
    o.z = acc[j][2] * inv;
    o.w = acc[j][3] * inv;
    *(float4*)(dst + (((size_t)(b * 81 + i * 9 + j) * 64 + h) << 7) + w0) = o;
  }
}

// ---------------------------------------------------------------------------
// Combine: out += channel-half-1 partial. 663,552 float4s, grid 2592 x 256.
// ---------------------------------------------------------------------------
__global__ __launch_bounds__(256) void combine_kernel(
    float* __restrict__ out, const float* __restrict__ part) {
  const size_t idx = (size_t)blockIdx.x * 256 + threadIdx.x;  // float4 index
  float4* o4       = (float4*)out;
  const float4* p4 = (const float4*)part;
  const float4 a = o4[idx], p = p4[idx];
  float4 rv;
  rv.x = a.x + p.x; rv.y = a.y + p.y; rv.z = a.z + p.z; rv.w = a.w + p.w;
  o4[idx] = rv;
}

// ---------------------------------------------------------------------------
extern "C" void kernel_launch(void* const* d_in, const int* in_sizes, int n_in,
                              void* d_out, int out_size, void* d_ws, size_t ws_size,
                              hipStream_t stream) {
  const float* feat1 = (const float*)d_in[0];
  const float* feat2 = (const float*)d_in[1];
  const float* w1    = (const float*)d_in[2];
  const float* b1    = (const float*)d_in[3];
  const float* w2    = (const float*)d_in[4];
  const float* b2    = (const float*)d_in[5];
  float* out = (float*)d_out;

  float* pooled = (float*)d_ws;                 // 82,944 floats
  float* At     = pooled + 82944;               // 82,944 floats
  float* cpart  = At + 82944;                   // 2,654,208 floats

  corr_pool_kernel<<<1024, 576, 0, stream>>>(feat1, feat2, pooled);
  mlp_kernel<<<4 * 81, 256, 0, stream>>>(pooled, w1, b1, w2, b2, At);
  out_kernel<<<2304, 64, 0, stream>>>(feat1, feat2, At, out, cpart);
  combine_kernel<<<2592, 256, 0, stream>>>(out, cpart);
}